// Round 10
// baseline (129.415 us; speedup 1.0000x reference)
//
#include <hip/hip_runtime.h>

typedef __attribute__((ext_vector_type(8))) short short8;
typedef __attribute__((ext_vector_type(16))) float f32x16;

#define B_    8
#define N_TOK 4096
#define C_    512
#define H_    16
#define K_TOK 1024
#define D_    64
#define BM    64
#define BK    64

// fp32 -> bf16, round-to-nearest-even
static __device__ inline ushort f2b(float f) {
  unsigned u = __builtin_bit_cast(unsigned, f);
  u += 0x7fff + ((u >> 16) & 1);
  return (ushort)(u >> 16);
}

// 16B gathered global -> linear LDS DMA (wave-uniform LDS base + lane*16)
static __device__ inline void gload_lds16(const ushort* g, ushort* l) {
  __builtin_amdgcn_global_load_lds(
      (const __attribute__((address_space(1))) unsigned int*)g,
      (__attribute__((address_space(3))) unsigned int*)l, 16, 0, 0);
}

// X fp32 [B][N][C] -> Xbf bf16 (halves gathered traffic; 8 elems/thread)
__global__ __launch_bounds__(256) void x_convert(const float* __restrict__ X,
                                                 ushort* __restrict__ Xb) {
  size_t base = ((size_t)blockIdx.x * 256 + threadIdx.x) * 8;
  float4 a = *reinterpret_cast<const float4*>(&X[base]);
  float4 b = *reinterpret_cast<const float4*>(&X[base + 4]);
  short8 o;
  o[0] = f2b(a.x); o[1] = f2b(a.y); o[2] = f2b(a.z); o[3] = f2b(a.w);
  o[4] = f2b(b.x); o[5] = f2b(b.y); o[6] = f2b(b.z); o[7] = f2b(b.w);
  *reinterpret_cast<short8*>(&Xb[base]) = o;
}

// W fp32 [H][C][D] -> WT bf16 [H][D][C], LDS-tiled transpose
__global__ __launch_bounds__(256) void wt_convert(const float* __restrict__ W,
                                                  ushort* __restrict__ WT) {
  __shared__ float tile[64][65];
  int h   = blockIdx.x >> 3;
  int kc0 = (blockIdx.x & 7) << 6;
  int t   = threadIdx.x;
  const float* Wh = W + ((size_t)h * C_ + kc0) * D_;
#pragma unroll
  for (int p = 0; p < 4; ++p) {
    int k  = p * 16 + (t >> 4);
    int n4 = (t & 15) * 4;
    float4 v = *reinterpret_cast<const float4*>(&Wh[k * D_ + n4]);
    tile[k][n4 + 0] = v.x; tile[k][n4 + 1] = v.y;
    tile[k][n4 + 2] = v.z; tile[k][n4 + 3] = v.w;
  }
  __syncthreads();
  ushort* WTh = WT + (size_t)h * D_ * C_;
#pragma unroll
  for (int p = 0; p < 4; ++p) {
    int n  = p * 16 + (t >> 4);
    int k4 = (t & 15) * 4;
    ushort4 o;
    o.x = f2b(tile[k4 + 0][n]); o.y = f2b(tile[k4 + 1][n]);
    o.z = f2b(tile[k4 + 2][n]); o.w = f2b(tile[k4 + 3][n]);
    *reinterpret_cast<ushort4*>(&WTh[n * C_ + kc0 + k4]) = o;
  }
}

// bf16 gather-GEMM: global_load_lds DMA staging (no VGPR roundtrip, no cvt in
// loop), double-buffered LDS, 2-phase pipeline (stage kc+1 || compute kc).
__global__ __launch_bounds__(256) void gather_gemm(
    const ushort* __restrict__ Xbf, const int* __restrict__ ind,
    const ushort* __restrict__ WT, float* __restrict__ out) {
  __shared__ ushort As[2][BM * BK];  // 2 x 8 KB
  __shared__ ushort Bs[2][D_ * BK];  // 2 x 8 KB
  __shared__ int inds[BM];

  int bid = blockIdx.x;
  // XCD swizzle: 2048 blocks, 8 XCDs -> XCD x gets batch x (Xbf[b] L2/L3-local)
  int nb = (bid & 7) * 256 + (bid >> 3);
  int b  = nb >> 8;
  int h  = (nb >> 4) & 15;
  int mt = nb & 15;

  int tid = threadIdx.x;
  if (tid < BM) inds[tid] = ind[(size_t)(b * H_ + h) * K_TOK + mt * BM + tid];
  __syncthreads();

  int lane = tid & 63;
  int w    = tid >> 6;

  // staging geometry: wave w stages rows w*16..w*16+15 (2 DMA instrs of 8 rows)
  int rA0 = w * 16 + (lane >> 3);   // instr-0 row
  int rA1 = rA0 + 8;                // instr-1 row
  int cA  = lane & 7;               // 16B chunk
  const ushort* Xb = Xbf + (size_t)b * N_TOK * C_;
  const ushort* wth = WT + (size_t)(h * D_) * C_;
  // pre-swizzled per-lane global sources (swizzle applied on source => LDS linear,
  // read side XORs it back)
  const ushort* gA0 = Xb + (size_t)inds[rA0] * C_ + ((cA ^ (rA0 & 7)) << 3);
  const ushort* gA1 = Xb + (size_t)inds[rA1] * C_ + ((cA ^ (rA1 & 7)) << 3);
  const ushort* gB0 = wth + rA0 * C_ + ((cA ^ (rA0 & 7)) << 3);
  const ushort* gB1 = wth + rA1 * C_ + ((cA ^ (rA1 & 7)) << 3);
  int lb0 = (w * 16) * 64;          // wave-uniform LDS bases (ushort idx)
  int lb1 = lb0 + 8 * 64;

  f32x16 acc = {};
  int rh = w >> 1;                  // output quadrant
  int ch = w & 1;
  int arow = rh * 32 + (lane & 31);
  int brow = ch * 32 + (lane & 31);
  int hi   = lane >> 5;

  // prologue: stage kc=0 into buf 0
  gload_lds16(gA0, &As[0][lb0]);
  gload_lds16(gA1, &As[0][lb1]);
  gload_lds16(gB0, &Bs[0][lb0]);
  gload_lds16(gB1, &Bs[0][lb1]);
  __syncthreads();                  // drains vmcnt(0) + barrier

  int buf = 0;
  for (int kc = 0; kc < C_ / BK; ++kc) {
    // prefetch next kc-tile into the other buffer (in flight across compute)
    if (kc < C_ / BK - 1) {
      int o = (kc + 1) * BK;
      gload_lds16(gA0 + o, &As[buf ^ 1][lb0]);
      gload_lds16(gA1 + o, &As[buf ^ 1][lb1]);
      gload_lds16(gB0 + o, &Bs[buf ^ 1][lb0]);
      gload_lds16(gB1 + o, &Bs[buf ^ 1][lb1]);
    }
    // compute current buffer: 4 x mfma 32x32x16 (wave owns 32x32 quadrant)
#pragma unroll
    for (int kk = 0; kk < 4; ++kk) {
      int ka = kk * 2 + hi;
      short8 af = *reinterpret_cast<short8*>(
          &As[buf][arow * 64 + ((ka ^ (arow & 7)) << 3)]);
      short8 bf = *reinterpret_cast<short8*>(
          &Bs[buf][brow * 64 + ((ka ^ (brow & 7)) << 3)]);
      acc = __builtin_amdgcn_mfma_f32_32x32x16_bf16(af, bf, acc, 0, 0, 0);
    }
    __syncthreads();                // drains prefetch DMA + read completion
    buf ^= 1;
  }

  // epilogue: C/D layout col=lane&31, row=(reg&3)+8*(reg>>2)+4*(lane>>5)
  size_t obase = ((size_t)(b * H_ + h) * K_TOK + mt * BM + rh * 32) * D_;
  int col = ch * 32 + (lane & 31);
#pragma unroll
  for (int reg = 0; reg < 16; ++reg) {
    int r = (reg & 3) + 8 * (reg >> 2) + 4 * hi;
    out[obase + (size_t)r * D_ + col] = acc[reg];
  }
}

extern "C" void kernel_launch(void* const* d_in, const int* in_sizes, int n_in,
                              void* d_out, int out_size, void* d_ws, size_t ws_size,
                              hipStream_t stream) {
  const float* X  = (const float*)d_in[0];
  const int*  ind = (const int*)d_in[1];
  const float* W  = (const float*)d_in[2];
  float* out = (float*)d_out;
  ushort* WS  = (ushort*)d_ws;
  ushort* WT  = WS;                 // 1 MB bf16 [H][D][C]
  ushort* Xbf = WS + (size_t)H_ * D_ * C_;   // 33.5 MB bf16 [B][N][C]

  x_convert<<<dim3(8192), dim3(256), 0, stream>>>(X, Xbf);
  wt_convert<<<dim3(128), dim3(256), 0, stream>>>(W, WT);
  gather_gemm<<<dim3(2048), dim3(256), 0, stream>>>(Xbf, ind, WT, out);
}

// Round 13
// 128.131 us; speedup vs baseline: 1.0100x; 1.0100x over previous
//
#include <hip/hip_runtime.h>

typedef __attribute__((ext_vector_type(8))) short short8;
typedef __attribute__((ext_vector_type(16))) float f32x16;

#define B_    8
#define N_TOK 4096
#define C_    512
#define H_    16
#define K_TOK 1024
#define D_    64
#define BM    64
#define BK    64

// fp32 -> bf16, round-to-nearest-even
static __device__ inline ushort f2b(float f) {
  unsigned u = __builtin_bit_cast(unsigned, f);
  u += 0x7fff + ((u >> 16) & 1);
  return (ushort)(u >> 16);
}

// 16B gathered global -> linear LDS DMA (wave-uniform LDS base + lane*16)
static __device__ inline void gload_lds16(const ushort* g, ushort* l) {
  __builtin_amdgcn_global_load_lds(
      (const __attribute__((address_space(1))) unsigned int*)g,
      (__attribute__((address_space(3))) unsigned int*)l, 16, 0, 0);
}

// X fp32 [B][N][C] -> Xbf bf16 (halves gathered traffic; 8 elems/thread)
__global__ __launch_bounds__(256) void x_convert(const float* __restrict__ X,
                                                 ushort* __restrict__ Xb) {
  size_t base = ((size_t)blockIdx.x * 256 + threadIdx.x) * 8;
  float4 a = *reinterpret_cast<const float4*>(&X[base]);
  float4 b = *reinterpret_cast<const float4*>(&X[base + 4]);
  short8 o;
  o[0] = f2b(a.x); o[1] = f2b(a.y); o[2] = f2b(a.z); o[3] = f2b(a.w);
  o[4] = f2b(b.x); o[5] = f2b(b.y); o[6] = f2b(b.z); o[7] = f2b(b.w);
  *reinterpret_cast<short8*>(&Xb[base]) = o;
}

// W fp32 [H][C][D] -> WT bf16 [H][D][C], LDS-tiled transpose
__global__ __launch_bounds__(256) void wt_convert(const float* __restrict__ W,
                                                  ushort* __restrict__ WT) {
  __shared__ float tile[64][65];
  int h   = blockIdx.x >> 3;
  int kc0 = (blockIdx.x & 7) << 6;
  int t   = threadIdx.x;
  const float* Wh = W + ((size_t)h * C_ + kc0) * D_;
#pragma unroll
  for (int p = 0; p < 4; ++p) {
    int k  = p * 16 + (t >> 4);
    int n4 = (t & 15) * 4;
    float4 v = *reinterpret_cast<const float4*>(&Wh[k * D_ + n4]);
    tile[k][n4 + 0] = v.x; tile[k][n4 + 1] = v.y;
    tile[k][n4 + 2] = v.z; tile[k][n4 + 3] = v.w;
  }
  __syncthreads();
  ushort* WTh = WT + (size_t)h * D_ * C_;
#pragma unroll
  for (int p = 0; p < 4; ++p) {
    int n  = p * 16 + (t >> 4);
    int k4 = (t & 15) * 4;
    ushort4 o;
    o.x = f2b(tile[k4 + 0][n]); o.y = f2b(tile[k4 + 1][n]);
    o.z = f2b(tile[k4 + 2][n]); o.w = f2b(tile[k4 + 3][n]);
    *reinterpret_cast<ushort4*>(&WTh[n * C_ + kc0 + k4]) = o;
  }
}

// bf16 gather-GEMM: DMA double-buffer with COUNTED vmcnt (T4) — the barrier no
// longer drains the kc+1 prefetch; only kc's DMAs (a full iteration old) are
// waited. Raw s_barrier pairs replace __syncthreads (which drains vmcnt(0)).
__global__ __launch_bounds__(256) void gather_gemm(
    const ushort* __restrict__ Xbf, const int* __restrict__ ind,
    const ushort* __restrict__ WT, float* __restrict__ out) {
  __shared__ ushort As[2][BM * BK];  // 2 x 8 KB
  __shared__ ushort Bs[2][D_ * BK];  // 2 x 8 KB
  __shared__ int inds[BM];

  int bid = blockIdx.x;
  // XCD swizzle: 2048 blocks, 8 XCDs -> XCD x gets batch x (Xbf[b] L2-local)
  int nb = (bid & 7) * 256 + (bid >> 3);
  int b  = nb >> 8;
  int h  = (nb >> 4) & 15;
  int mt = nb & 15;

  int tid = threadIdx.x;
  if (tid < BM) inds[tid] = ind[(size_t)(b * H_ + h) * K_TOK + mt * BM + tid];
  __syncthreads();

  int lane = tid & 63;
  int w    = tid >> 6;

  // staging geometry: wave w stages rows w*16..w*16+15 (2 DMA instrs of 8 rows)
  int rA0 = w * 16 + (lane >> 3);   // instr-0 row
  int rA1 = rA0 + 8;                // instr-1 row
  int cA  = lane & 7;               // 16B chunk
  const ushort* Xb = Xbf + (size_t)b * N_TOK * C_;
  const ushort* wth = WT + (size_t)(h * D_) * C_;
  // pre-swizzled per-lane global sources (swizzle on source => LDS linear,
  // read side XORs it back — same involution both sides)
  const ushort* gA0 = Xb + (size_t)inds[rA0] * C_ + ((cA ^ (rA0 & 7)) << 3);
  const ushort* gA1 = Xb + (size_t)inds[rA1] * C_ + ((cA ^ (rA1 & 7)) << 3);
  const ushort* gB0 = wth + rA0 * C_ + ((cA ^ (rA0 & 7)) << 3);
  const ushort* gB1 = wth + rA1 * C_ + ((cA ^ (rA1 & 7)) << 3);
  int lb0 = (w * 16) * 64;          // wave-uniform LDS bases (ushort idx)
  int lb1 = lb0 + 8 * 64;

  f32x16 acc = {};
  int rh = w >> 1;                  // output quadrant
  int ch = w & 1;
  int arow = rh * 32 + (lane & 31);
  int brow = ch * 32 + (lane & 31);
  int hi   = lane >> 5;

  // prologue: stage kc=0 into buf 0 (4 DMAs outstanding)
  gload_lds16(gA0, &As[0][lb0]);
  gload_lds16(gA1, &As[0][lb1]);
  gload_lds16(gB0, &Bs[0][lb0]);
  gload_lds16(gB1, &Bs[0][lb1]);

  int buf = 0;
#pragma unroll
  for (int kc = 0; kc < C_ / BK; ++kc) {
    if (kc < C_ / BK - 1) {
      // issue stage(kc+1) into buf^1 — stays in flight across compute(kc)
      int o = (kc + 1) * BK;
      gload_lds16(gA0 + o, &As[buf ^ 1][lb0]);
      gload_lds16(gA1 + o, &As[buf ^ 1][lb1]);
      gload_lds16(gB0 + o, &Bs[buf ^ 1][lb0]);
      gload_lds16(gB1 + o, &Bs[buf ^ 1][lb1]);
      // wait only the OLDEST 4 (kc's stage, issued a full iteration ago)
      asm volatile("s_waitcnt vmcnt(4)" ::: "memory");
    } else {
      asm volatile("s_waitcnt vmcnt(0)" ::: "memory");
    }
    __builtin_amdgcn_s_barrier();          // all waves' kc-stages now landed
    __builtin_amdgcn_sched_barrier(0);     // pin ds_reads behind the wait

    // compute current buffer: 4 x mfma 32x32x16 (wave owns 32x32 quadrant)
#pragma unroll
    for (int kk = 0; kk < 4; ++kk) {
      int ka = kk * 2 + hi;
      short8 af = *reinterpret_cast<short8*>(
          &As[buf][arow * 64 + ((ka ^ (arow & 7)) << 3)]);
      short8 bf = *reinterpret_cast<short8*>(
          &Bs[buf][brow * 64 + ((ka ^ (brow & 7)) << 3)]);
      acc = __builtin_amdgcn_mfma_f32_32x32x16_bf16(af, bf, acc, 0, 0, 0);
    }
    __builtin_amdgcn_sched_barrier(0);     // keep reads inside the phase
    __builtin_amdgcn_s_barrier();          // readers done before buf overwrite
    buf ^= 1;
  }

  // epilogue: C/D layout col=lane&31, row=(reg&3)+8*(reg>>2)+4*(lane>>5)
  size_t obase = ((size_t)(b * H_ + h) * K_TOK + mt * BM + rh * 32) * D_;
  int col = ch * 32 + (lane & 31);
#pragma unroll
  for (int reg = 0; reg < 16; ++reg) {
    int r = (reg & 3) + 8 * (reg >> 2) + 4 * hi;
    out[obase + (size_t)r * D_ + col] = acc[reg];
  }
}

extern "C" void kernel_launch(void* const* d_in, const int* in_sizes, int n_in,
                              void* d_out, int out_size, void* d_ws, size_t ws_size,
                              hipStream_t stream) {
  const float* X  = (const float*)d_in[0];
  const int*  ind = (const int*)d_in[1];
  const float* W  = (const float*)d_in[2];
  float* out = (float*)d_out;
  ushort* WS  = (ushort*)d_ws;
  ushort* WT  = WS;                 // 1 MB bf16 [H][D][C]
  ushort* Xbf = WS + (size_t)H_ * D_ * C_;   // 33.5 MB bf16 [B][N][C]

  x_convert<<<dim3(8192), dim3(256), 0, stream>>>(X, Xbf);
  wt_convert<<<dim3(128), dim3(256), 0, stream>>>(W, WT);
  gather_gemm<<<dim3(2048), dim3(256), 0, stream>>>(Xbf, ind, WT, out);
}